// Round 3
// baseline (698.436 us; speedup 1.0000x reference)
//
#include <hip/hip_runtime.h>
#include <cstdint>
#include <cstddef>

typedef __bf16 bf16x8 __attribute__((ext_vector_type(8)));
typedef float f32x4 __attribute__((ext_vector_type(4)));

__device__ __forceinline__ float bf2f(unsigned short u){
  unsigned int x = ((unsigned int)u) << 16;
  return __builtin_bit_cast(float, x);
}
__device__ __forceinline__ unsigned short f2bf(float f){
  unsigned int x = __builtin_bit_cast(unsigned int, f);
  x += 0x7fffu + ((x >> 16) & 1u);
  return (unsigned short)(x >> 16);
}

// ---------------- dtype detect + canonicalize ----------------
// fp32 misread as bf16: low mantissa halves carry random exponent fields;
// real bf16 activations ~N(0,1) never have exp >= 0xC0 (|v| >= 2^65).
__global__ void k_detect(const unsigned short* __restrict__ xs, int* __restrict__ flag){
  __shared__ int found;
  if (threadIdx.x == 0) found = 0;
  __syncthreads();
  for (int i = threadIdx.x; i < 4096; i += 256){
    unsigned short u = xs[i];
    int expo = (u >> 7) & 0xFF;
    if (expo >= 0xC0) atomicOr(&found, 1);
  }
  __syncthreads();
  if (threadIdx.x == 0) flag[0] = found;
}

__global__ void k_canon_f32(const void* __restrict__ src, float* __restrict__ dst,
                            int n, const int* __restrict__ flag){
  int i = blockIdx.x*256 + threadIdx.x;
  if (i < n){
    dst[i] = flag[0] ? ((const float*)src)[i]
                     : bf2f(((const unsigned short*)src)[i]);
  }
}

__global__ void k_canon_bf16(const void* __restrict__ src, unsigned short* __restrict__ dst,
                             int n, const int* __restrict__ flag){
  int i = blockIdx.x*256 + threadIdx.x;
  if (i < n){
    dst[i] = flag[0] ? f2bf(((const float*)src)[i])
                     : ((const unsigned short*)src)[i];
  }
}

// weight (K x M) -> WT[m*128 + k] (row length hardcoded 128 = K for all layers)
__global__ void k_canonT(const void* __restrict__ src, unsigned short* __restrict__ dst,
                         int K, int M, const int* __restrict__ flag){
  int idx = blockIdx.x*256 + threadIdx.x;
  if (idx < K*M){
    int k = idx / M, m = idx % M;
    unsigned short v = flag[0] ? f2bf(((const float*)src)[idx])
                               : ((const unsigned short*)src)[idx];
    dst[m*128 + k] = v;
  }
}

// ---------------- graph build ----------------

__global__ void k_hist(const int* __restrict__ ei, const float* __restrict__ ewc,
                       int* __restrict__ cnt, float* __restrict__ wsum, int E, int n){
  int e = blockIdx.x*256 + threadIdx.x;
  if (e < E){
    int d = ei[E + e];
    if ((unsigned)d < (unsigned)n){
      atomicAdd(&cnt[d], 1);
      atomicAdd(&wsum[d], ewc[e]);
    }
  }
}

// rowptr[i+1] = sum_{j<=i} (cnt[j]+1); single block, wave-shuffle scan
__global__ void k_scan(const int* __restrict__ cnt, int* __restrict__ rowptr, int n){
  __shared__ int wsums[16];
  __shared__ int chunk_total;
  __shared__ int carry;
  int tid = threadIdx.x;             // 1024 threads
  int lane = tid & 63, wid = tid >> 6;
  if (tid == 0){ carry = 0; rowptr[0] = 0; }
  __syncthreads();
  for (int base = 0; base < n; base += 1024){
    int i = base + tid;
    int v = (i < n) ? (cnt[i] + 1) : 0;
    int sv = v;
    for (int off = 1; off < 64; off <<= 1){
      int t = __shfl_up(sv, off);
      if (lane >= off) sv += t;
    }
    if (lane == 63) wsums[wid] = sv;
    __syncthreads();
    if (tid == 0){
      int acc = 0;
      for (int w2 = 0; w2 < 16; w2++){ int t = wsums[w2]; wsums[w2] = acc; acc += t; }
      chunk_total = acc;
    }
    __syncthreads();
    if (i < n) rowptr[i + 1] = carry + wsums[wid] + sv;
    __syncthreads();
    if (tid == 0) carry += chunk_total;
    __syncthreads();
  }
}

__global__ void k_self(const int* __restrict__ rowptr, const int* __restrict__ cnt,
                       const float* __restrict__ wsum, int* __restrict__ fill,
                       int* __restrict__ csr_src, float* __restrict__ csr_w, int n, int ET){
  int i = blockIdx.x*256 + threadIdx.x;
  if (i < n){
    fill[i] = rowptr[i];
    int slot = rowptr[i+1] - 1;
    if ((unsigned)slot < (unsigned)ET){
      csr_src[slot] = i;
      csr_w[slot] = wsum[i] / fmaxf((float)cnt[i], 1.0f);
    }
  }
}

__global__ void k_scatter(const int* __restrict__ ei, const float* __restrict__ ewc,
                          int* __restrict__ fill, int* __restrict__ csr_src,
                          float* __restrict__ csr_w, int E, int n, int ET){
  int e = blockIdx.x*256 + threadIdx.x;
  if (e < E){
    int s = ei[e], d = ei[E + e];
    if ((unsigned)d < (unsigned)n){
      int pos = atomicAdd(&fill[d], 1);
      if ((unsigned)pos < (unsigned)ET){
        csr_src[pos] = s;
        csr_w[pos] = ewc[e];
      }
    }
  }
}

// ---------------- fused xl/xr GEMM: out(f32) = A(nrows x 128, bf16) @ W(128 x ncols) + b ----------------
// one wave per block: 64 rows x 64 cols via 16 MFMA 16x16x32 tiles.

__global__ __launch_bounds__(64) void k_gemm(
  const unsigned short* __restrict__ A,
  const unsigned short* __restrict__ WTl, const unsigned short* __restrict__ WTr,
  const float* __restrict__ bl, const float* __restrict__ br,
  float* __restrict__ outL, float* __restrict__ outR,
  int nrows, int ncols)
{
  int lane = threadIdx.x;
  int q = lane >> 4, rr = lane & 15;
  int r0 = blockIdx.x * 64;
  int per = ncols >> 6;
  int slice = blockIdx.y;
  bool isR = slice >= per;
  const unsigned short* WT  = isR ? WTr : WTl;
  const float* bia          = isR ? br  : bl;
  float* out                = isR ? outR : outL;
  int n0 = (slice - (isR ? per : 0)) * 64;

  f32x4 acc[4][4];
  for (int a = 0; a < 4; a++)
    for (int b = 0; b < 4; b++)
      acc[a][b] = (f32x4){0.f, 0.f, 0.f, 0.f};

  for (int kc = 0; kc < 4; kc++){
    bf16x8 af[4], bfr[4];
    for (int rt = 0; rt < 4; rt++){
      int row = r0 + rt*16 + rr;
      if (row >= nrows) row = nrows - 1;            // clamp: OOB rows never stored
      af[rt] = *(const bf16x8*)(A + (size_t)row*128 + kc*32 + q*8);
    }
    for (int ct = 0; ct < 4; ct++){
      bfr[ct] = *(const bf16x8*)(WT + (size_t)(n0 + ct*16 + rr)*128 + kc*32 + q*8);
    }
    for (int rt = 0; rt < 4; rt++)
      for (int ct = 0; ct < 4; ct++)
        acc[rt][ct] = __builtin_amdgcn_mfma_f32_16x16x32_bf16(af[rt], bfr[ct], acc[rt][ct], 0, 0, 0);
  }

  // C/D layout: col = lane&15, row = (lane>>4)*4 + reg  [m89/m91-verified]
  for (int ct = 0; ct < 4; ct++){
    int col = n0 + ct*16 + rr;
    float bv = bia[col];
    for (int rt = 0; rt < 4; rt++){
      for (int t = 0; t < 4; t++){
        int row = r0 + rt*16 + q*4 + t;
        if (row < nrows)
          out[(size_t)row*ncols + col] = acc[rt][ct][t] + bv;
      }
    }
  }
}

// ---------------- fused edge scoring + online-softmax aggregation ----------------
// HID=128, HEADS=4 (C=32): one wave per dst node, lane holds channels 2l,2l+1;
// head h = lanes [16h,16h+16) so width-16 xor reduction == per-head dot.

__global__ __launch_bounds__(256) void k_edge128(
  const float* __restrict__ xl, const float* __restrict__ xr,
  const int* __restrict__ rowptr, const int* __restrict__ csr_src, const float* __restrict__ csr_w,
  const float* __restrict__ We, const float* __restrict__ att,
  const float* __restrict__ bias, unsigned short* __restrict__ out, int n, int ET)
{
  int wid = threadIdx.x >> 6;
  int lane = threadIdx.x & 63;
  int node = blockIdx.x*4 + wid;
  if (node >= n) return;
  int ch = lane*2;
  float we0 = We[ch],  we1 = We[ch+1];
  float at0 = att[ch], at1 = att[ch+1];   // att flat index == channel index (head-major concat)
  float2 xrv = *(const float2*)(xr + (size_t)node*128 + ch);
  float fxr0 = xrv.x, fxr1 = xrv.y;
  int beg = rowptr[node], end = rowptr[node+1];
  if (beg < 0) beg = 0;
  if (end > ET) end = ET;
  float m = -1e30f, l = 0.f, a0 = 0.f, a1 = 0.f;
  for (int base = beg; base < end; base += 64){
    int idx = base + lane;
    int   sv = 0; float wv = 0.f;
    if (idx < end){ sv = csr_src[idx]; wv = csr_w[idx]; }
    if ((unsigned)sv >= (unsigned)n) sv = 0;
    int c = end - base; if (c > 64) c = 64;
    for (int i = 0; i < c; i++){
      int   s = __shfl(sv, i);
      float w = __shfl(wv, i);
      float2 xv = *(const float2*)(xl + (size_t)s*128 + ch);
      float x0 = xv.x, x1 = xv.y;
      float t0 = x0 + fxr0 + w*we0;
      float t1 = x1 + fxr1 + w*we1;
      t0 = t0 > 0.f ? t0 : 0.2f*t0;       // leaky_relu
      t1 = t1 > 0.f ? t1 : 0.2f*t1;
      float p = t0*at0 + t1*at1;
      p += __shfl_xor(p, 1, 16);
      p += __shfl_xor(p, 2, 16);
      p += __shfl_xor(p, 4, 16);
      p += __shfl_xor(p, 8, 16);
      float nm = fmaxf(m, p);
      float sc = __expf(m - nm);
      float pe = __expf(p - nm);
      l  = l*sc  + pe;
      a0 = a0*sc + pe*x0;
      a1 = a1*sc + pe*x1;
      m = nm;
    }
  }
  float inv = 1.0f / (l + 1e-16f);
  float o0 = a0*inv + bias[ch];
  float o1 = a1*inv + bias[ch+1];
  o0 = o0 > 0.f ? o0 : (__expf(o0) - 1.0f);   // ELU (layers 0,1)
  o1 = o1 > 0.f ? o1 : (__expf(o1) - 1.0f);
  unsigned int packed = (unsigned int)f2bf(o0) | ((unsigned int)f2bf(o1) << 16);
  *(unsigned int*)(out + (size_t)node*128 + ch) = packed;   // bf16 for next layer's GEMM
}

// OUT=64, 1 head (C=64): lane == channel, full-wave reduction; no ELU; mean over 1 head = identity.
// Output dtype follows input dtype: fp32 if flag, else bf16.
__global__ __launch_bounds__(256) void k_edge64(
  const float* __restrict__ xl, const float* __restrict__ xr,
  const int* __restrict__ rowptr, const int* __restrict__ csr_src, const float* __restrict__ csr_w,
  const float* __restrict__ We, const float* __restrict__ att,
  const float* __restrict__ bias, void* __restrict__ out, int n, int ET,
  const int* __restrict__ flag)
{
  int wid = threadIdx.x >> 6;
  int lane = threadIdx.x & 63;
  int node = blockIdx.x*4 + wid;
  if (node >= n) return;
  float we0 = We[lane];
  float at0 = att[lane];
  float fxr0 = xr[(size_t)node*64 + lane];
  int beg = rowptr[node], end = rowptr[node+1];
  if (beg < 0) beg = 0;
  if (end > ET) end = ET;
  float m = -1e30f, l = 0.f, a0 = 0.f;
  for (int base = beg; base < end; base += 64){
    int idx = base + lane;
    int   sv = 0; float wv = 0.f;
    if (idx < end){ sv = csr_src[idx]; wv = csr_w[idx]; }
    if ((unsigned)sv >= (unsigned)n) sv = 0;
    int c = end - base; if (c > 64) c = 64;
    for (int i = 0; i < c; i++){
      int   s = __shfl(sv, i);
      float w = __shfl(wv, i);
      float x0 = xl[(size_t)s*64 + lane];
      float t0 = x0 + fxr0 + w*we0;
      t0 = t0 > 0.f ? t0 : 0.2f*t0;
      float p = t0*at0;
      p += __shfl_xor(p, 1);
      p += __shfl_xor(p, 2);
      p += __shfl_xor(p, 4);
      p += __shfl_xor(p, 8);
      p += __shfl_xor(p, 16);
      p += __shfl_xor(p, 32);
      float nm = fmaxf(m, p);
      float sc = __expf(m - nm);
      float pe = __expf(p - nm);
      l  = l*sc  + pe;
      a0 = a0*sc + pe*x0;
      m = nm;
    }
  }
  float inv = 1.0f / (l + 1e-16f);
  float res = a0*inv + bias[lane];
  size_t oi = (size_t)node*64 + lane;
  if (flag[0]) ((float*)out)[oi] = res;
  else         ((unsigned short*)out)[oi] = f2bf(res);
}

// ---------------- host ----------------

extern "C" void kernel_launch(void* const* d_in, const int* in_sizes, int n_in,
                              void* d_out, int out_size, void* d_ws, size_t ws_size,
                              hipStream_t stream)
{
  (void)n_in; (void)out_size; (void)ws_size;
  const void* x   = d_in[0];
  const int*  ei  = (const int*)d_in[1];
  const void* ew  = d_in[2];
  const void* Wl0 = d_in[3];  const void* bl0 = d_in[4];
  const void* Wr0 = d_in[5];  const void* br0 = d_in[6];
  const void* We0 = d_in[7];  const void* at0 = d_in[8];  const void* bi0 = d_in[9];
  const void* Wl1 = d_in[10]; const void* bl1 = d_in[11];
  const void* Wr1 = d_in[12]; const void* br1 = d_in[13];
  const void* We1 = d_in[14]; const void* at1 = d_in[15]; const void* bi1 = d_in[16];
  const void* Wl2 = d_in[17]; const void* bl2 = d_in[18];
  const void* Wr2 = d_in[19]; const void* br2 = d_in[20];
  const void* We2 = d_in[21]; const void* at2 = d_in[22]; const void* bi2 = d_in[23];

  const int N = in_sizes[0] / 128;
  const int E = in_sizes[2];
  const int ET = E + N;

  char* p = (char*)d_ws;
  size_t off = 0;
  auto carve = [&](size_t bytes)->void* {
    void* r = p + off;
    off = (off + bytes + 255) & ~(size_t)255;
    return r;
  };
  int*            flag    = (int*)carve(4);
  int*            cnt     = (int*)carve((size_t)N*4);
  float*          wsum    = (float*)carve((size_t)N*4);
  int*            rowptr  = (int*)carve((size_t)(N+1)*4);
  int*            fill    = (int*)carve((size_t)N*4);
  int*            csr_src = (int*)carve((size_t)ET*4);
  float*          csr_w   = (float*)carve((size_t)ET*4);
  float*          ewc     = (float*)carve((size_t)E*4);
  float*          bl0c    = (float*)carve(128*4); float* br0c = (float*)carve(128*4);
  float*          We0c    = (float*)carve(128*4); float* at0c = (float*)carve(128*4);
  float*          bi0c    = (float*)carve(128*4);
  float*          bl1c    = (float*)carve(128*4); float* br1c = (float*)carve(128*4);
  float*          We1c    = (float*)carve(128*4); float* at1c = (float*)carve(128*4);
  float*          bi1c    = (float*)carve(128*4);
  float*          bl2c    = (float*)carve(64*4);  float* br2c = (float*)carve(64*4);
  float*          We2c    = (float*)carve(64*4);  float* at2c = (float*)carve(64*4);
  float*          bi2c    = (float*)carve(64*4);
  unsigned short* WlT     = (unsigned short*)carve(128*128*2);
  unsigned short* WrT     = (unsigned short*)carve(128*128*2);
  unsigned short* xc      = (unsigned short*)carve((size_t)N*128*2);
  float*          xlb     = (float*)carve((size_t)N*128*4);
  float*          xrb     = (float*)carve((size_t)N*128*4);
  unsigned short* hb      = (unsigned short*)carve((size_t)N*128*2);

  hipMemsetAsync(cnt,  0, (size_t)N*4, stream);
  hipMemsetAsync(wsum, 0, (size_t)N*4, stream);

  // dtype detect + canonicalize
  k_detect<<<1, 256, 0, stream>>>((const unsigned short*)x, flag);
  k_canon_f32<<<(E+255)/256, 256, 0, stream>>>(ew, ewc, E, flag);
  k_canon_f32<<<1, 256, 0, stream>>>(bl0, bl0c, 128, flag);
  k_canon_f32<<<1, 256, 0, stream>>>(br0, br0c, 128, flag);
  k_canon_f32<<<1, 256, 0, stream>>>(We0, We0c, 128, flag);
  k_canon_f32<<<1, 256, 0, stream>>>(at0, at0c, 128, flag);
  k_canon_f32<<<1, 256, 0, stream>>>(bi0, bi0c, 128, flag);
  k_canon_f32<<<1, 256, 0, stream>>>(bl1, bl1c, 128, flag);
  k_canon_f32<<<1, 256, 0, stream>>>(br1, br1c, 128, flag);
  k_canon_f32<<<1, 256, 0, stream>>>(We1, We1c, 128, flag);
  k_canon_f32<<<1, 256, 0, stream>>>(at1, at1c, 128, flag);
  k_canon_f32<<<1, 256, 0, stream>>>(bi1, bi1c, 128, flag);
  k_canon_f32<<<1, 256, 0, stream>>>(bl2, bl2c, 64, flag);
  k_canon_f32<<<1, 256, 0, stream>>>(br2, br2c, 64, flag);
  k_canon_f32<<<1, 256, 0, stream>>>(We2, We2c, 64, flag);
  k_canon_f32<<<1, 256, 0, stream>>>(at2, at2c, 64, flag);
  k_canon_f32<<<1, 256, 0, stream>>>(bi2, bi2c, 64, flag);
  k_canon_bf16<<<((size_t)N*128+255)/256, 256, 0, stream>>>(x, xc, N*128, flag);

  // graph build
  k_hist   <<<(E+255)/256, 256, 0, stream>>>(ei, ewc, cnt, wsum, E, N);
  k_scan   <<<1, 1024, 0, stream>>>(cnt, rowptr, N);
  k_self   <<<(N+255)/256, 256, 0, stream>>>(rowptr, cnt, wsum, fill, csr_src, csr_w, N, ET);
  k_scatter<<<(E+255)/256, 256, 0, stream>>>(ei, ewc, fill, csr_src, csr_w, E, N, ET);

  const int rowBlocks = (N + 63) / 64;

  // layer 0
  k_canonT<<<(128*128+255)/256, 256, 0, stream>>>(Wl0, WlT, 128, 128, flag);
  k_canonT<<<(128*128+255)/256, 256, 0, stream>>>(Wr0, WrT, 128, 128, flag);
  k_gemm<<<dim3(rowBlocks, 4), 64, 0, stream>>>(xc, WlT, WrT, bl0c, br0c, xlb, xrb, N, 128);
  k_edge128<<<(N+3)/4, 256, 0, stream>>>(xlb, xrb, rowptr, csr_src, csr_w, We0c, at0c, bi0c, hb, N, ET);

  // layer 1
  k_canonT<<<(128*128+255)/256, 256, 0, stream>>>(Wl1, WlT, 128, 128, flag);
  k_canonT<<<(128*128+255)/256, 256, 0, stream>>>(Wr1, WrT, 128, 128, flag);
  k_gemm<<<dim3(rowBlocks, 4), 64, 0, stream>>>(hb, WlT, WrT, bl1c, br1c, xlb, xrb, N, 128);
  k_edge128<<<(N+3)/4, 256, 0, stream>>>(xlb, xrb, rowptr, csr_src, csr_w, We1c, at1c, bi1c, hb, N, ET);

  // layer 2 (OUT=64, 1 head, no ELU, output dtype follows flag)
  k_canonT<<<(128*64+255)/256, 256, 0, stream>>>(Wl2, WlT, 128, 64, flag);
  k_canonT<<<(128*64+255)/256, 256, 0, stream>>>(Wr2, WrT, 128, 64, flag);
  k_gemm<<<dim3(rowBlocks, 2), 64, 0, stream>>>(hb, WlT, WrT, bl2c, br2c, xlb, xrb, N, 64);
  k_edge64<<<(N+3)/4, 256, 0, stream>>>(xlb, xrb, rowptr, csr_src, csr_w, We2c, at2c, bi2c,
                                        d_out, N, ET, flag);
}

// Round 4
// 566.239 us; speedup vs baseline: 1.2335x; 1.2335x over previous
//
#include <hip/hip_runtime.h>
#include <cstdint>
#include <cstddef>

typedef __bf16 bf16x8 __attribute__((ext_vector_type(8)));
typedef float f32x4 __attribute__((ext_vector_type(4)));

__device__ __forceinline__ float bf2f(unsigned short u){
  unsigned int x = ((unsigned int)u) << 16;
  return __builtin_bit_cast(float, x);
}
__device__ __forceinline__ unsigned short f2bf(float f){
  unsigned int x = __builtin_bit_cast(unsigned int, f);
  x += 0x7fffu + ((x >> 16) & 1u);
  return (unsigned short)(x >> 16);
}

// ---------------- dtype detect + canonicalize ----------------
__global__ void k_detect(const unsigned short* __restrict__ xs, int* __restrict__ flag){
  __shared__ int found;
  if (threadIdx.x == 0) found = 0;
  __syncthreads();
  for (int i = threadIdx.x; i < 4096; i += 256){
    unsigned short u = xs[i];
    int expo = (u >> 7) & 0xFF;
    if (expo >= 0xC0) atomicOr(&found, 1);
  }
  __syncthreads();
  if (threadIdx.x == 0) flag[0] = found;
}

struct ParamTab {
  const void* src[17];
  float*      dst[17];
  int         n[17];
};
// one block per tensor (n <= 128)
__global__ void k_canon_params(ParamTab t, const int* __restrict__ flag){
  int b = blockIdx.x, i = threadIdx.x;
  if (i < t.n[b]){
    t.dst[b][i] = flag[0] ? ((const float*)t.src[b])[i]
                          : bf2f(((const unsigned short*)t.src[b])[i]);
  }
}

__global__ void k_canon_f32(const void* __restrict__ src, float* __restrict__ dst,
                            int n, const int* __restrict__ flag){
  int i = blockIdx.x*256 + threadIdx.x;
  if (i < n){
    dst[i] = flag[0] ? ((const float*)src)[i]
                     : bf2f(((const unsigned short*)src)[i]);
  }
}

__global__ void k_canon_bf16(const void* __restrict__ src, unsigned short* __restrict__ dst,
                             int n, const int* __restrict__ flag){
  int i = blockIdx.x*256 + threadIdx.x;
  if (i < n){
    dst[i] = flag[0] ? f2bf(((const float*)src)[i])
                     : ((const unsigned short*)src)[i];
  }
}

struct WTab {
  const void* src[6];
  unsigned short* dst[6];
  int M[6];       // K x M, K == 128 always; dst row stride 128
};
// grid: dim3(64, 6); tensor b = blockIdx.y, elements 128*M[b]
__global__ void k_canonT(WTab t, const int* __restrict__ flag){
  int b = blockIdx.y;
  int M = t.M[b];
  int idx = blockIdx.x*256 + threadIdx.x;
  if (idx < 128*M){
    int k = idx / M, m = idx % M;
    unsigned short v = flag[0] ? f2bf(((const float*)t.src[b])[idx])
                               : ((const unsigned short*)t.src[b])[idx];
    t.dst[b][m*128 + k] = v;
  }
}

// ---------------- graph build ----------------

__global__ void k_hist(const int* __restrict__ ei, const float* __restrict__ ewc,
                       int* __restrict__ cnt, float* __restrict__ wsum, int E, int n){
  int e = blockIdx.x*256 + threadIdx.x;
  if (e < E){
    int d = ei[E + e];
    if ((unsigned)d < (unsigned)n){
      atomicAdd(&cnt[d], 1);
      atomicAdd(&wsum[d], ewc[e]);
    }
  }
}

// 3-phase scan of (cnt[i]+1) -> rowptr (exclusive, rowptr[0]=0)
__global__ void k_scan1(const int* __restrict__ cnt, int* __restrict__ bsum, int n){
  int i = blockIdx.x*256 + threadIdx.x;
  int lane = threadIdx.x & 63, w = threadIdx.x >> 6;
  int v = (i < n) ? cnt[i] + 1 : 0;
  for (int off = 32; off; off >>= 1) v += __shfl_down(v, off);
  __shared__ int ws[4];
  if (lane == 0) ws[w] = v;
  __syncthreads();
  if (threadIdx.x == 0) bsum[blockIdx.x] = ws[0] + ws[1] + ws[2] + ws[3];
}

// single block, B <= 1024: exclusive scan of bsum -> boff
__global__ void k_scan2(const int* __restrict__ bsum, int* __restrict__ boff, int B){
  int tid = threadIdx.x, lane = tid & 63, w = tid >> 6;
  __shared__ int ws[16];
  int v = (tid < B) ? bsum[tid] : 0;
  int sv = v;
  for (int off = 1; off < 64; off <<= 1){
    int t = __shfl_up(sv, off);
    if (lane >= off) sv += t;
  }
  if (lane == 63) ws[w] = sv;
  __syncthreads();
  if (tid == 0){
    int acc = 0;
    for (int k = 0; k < 16; k++){ int t = ws[k]; ws[k] = acc; acc += t; }
  }
  __syncthreads();
  if (tid < B) boff[tid] = ws[w] + sv - v;
}

__global__ void k_scan3(const int* __restrict__ cnt, const int* __restrict__ boff,
                        int* __restrict__ rowptr, int n){
  int b = blockIdx.x, tid = threadIdx.x;
  int i = b*256 + tid;
  int lane = tid & 63, w = tid >> 6;
  __shared__ int ws[4];
  int v = (i < n) ? cnt[i] + 1 : 0;
  int sv = v;
  for (int off = 1; off < 64; off <<= 1){
    int t = __shfl_up(sv, off);
    if (lane >= off) sv += t;
  }
  if (lane == 63) ws[w] = sv;
  __syncthreads();
  if (tid == 0){
    int acc = 0;
    for (int k = 0; k < 4; k++){ int t = ws[k]; ws[k] = acc; acc += t; }
  }
  __syncthreads();
  if (i < n) rowptr[i + 1] = boff[b] + ws[w] + sv;
  if (i == 0) rowptr[0] = 0;
}

__global__ void k_self(const int* __restrict__ rowptr, const int* __restrict__ cnt,
                       const float* __restrict__ wsum, int* __restrict__ fill,
                       int* __restrict__ csr_src, float* __restrict__ csr_w, int n, int ET){
  int i = blockIdx.x*256 + threadIdx.x;
  if (i < n){
    fill[i] = rowptr[i];
    int slot = rowptr[i+1] - 1;
    if ((unsigned)slot < (unsigned)ET){
      csr_src[slot] = i;
      csr_w[slot] = wsum[i] / fmaxf((float)cnt[i], 1.0f);
    }
  }
}

__global__ void k_scatter(const int* __restrict__ ei, const float* __restrict__ ewc,
                          int* __restrict__ fill, int* __restrict__ csr_src,
                          float* __restrict__ csr_w, int E, int n, int ET){
  int e = blockIdx.x*256 + threadIdx.x;
  if (e < E){
    int s = ei[e], d = ei[E + e];
    if ((unsigned)d < (unsigned)n){
      int pos = atomicAdd(&fill[d], 1);
      if ((unsigned)pos < (unsigned)ET){
        csr_src[pos] = s;
        csr_w[pos] = ewc[e];
      }
    }
  }
}

// ---------------- fused xl/xr GEMM (bf16 MFMA, f32 out) ----------------

__global__ __launch_bounds__(64) void k_gemm(
  const unsigned short* __restrict__ A,
  const unsigned short* __restrict__ WTl, const unsigned short* __restrict__ WTr,
  const float* __restrict__ bl, const float* __restrict__ br,
  float* __restrict__ outL, float* __restrict__ outR,
  int nrows, int ncols)
{
  int lane = threadIdx.x;
  int q = lane >> 4, rr = lane & 15;
  int r0 = blockIdx.x * 64;
  int per = ncols >> 6;
  int slice = blockIdx.y;
  bool isR = slice >= per;
  const unsigned short* WT  = isR ? WTr : WTl;
  const float* bia          = isR ? br  : bl;
  float* out                = isR ? outR : outL;
  int n0 = (slice - (isR ? per : 0)) * 64;

  f32x4 acc[4][4];
  for (int a = 0; a < 4; a++)
    for (int b = 0; b < 4; b++)
      acc[a][b] = (f32x4){0.f, 0.f, 0.f, 0.f};

  for (int kc = 0; kc < 4; kc++){
    bf16x8 af[4], bfr[4];
    for (int rt = 0; rt < 4; rt++){
      int row = r0 + rt*16 + rr;
      if (row >= nrows) row = nrows - 1;
      af[rt] = *(const bf16x8*)(A + (size_t)row*128 + kc*32 + q*8);
    }
    for (int ct = 0; ct < 4; ct++){
      bfr[ct] = *(const bf16x8*)(WT + (size_t)(n0 + ct*16 + rr)*128 + kc*32 + q*8);
    }
    for (int rt = 0; rt < 4; rt++)
      for (int ct = 0; ct < 4; ct++)
        acc[rt][ct] = __builtin_amdgcn_mfma_f32_16x16x32_bf16(af[rt], bfr[ct], acc[rt][ct], 0, 0, 0);
  }

  for (int ct = 0; ct < 4; ct++){
    int col = n0 + ct*16 + rr;
    float bv = bia[col];
    for (int rt = 0; rt < 4; rt++){
      for (int t = 0; t < 4; t++){
        int row = r0 + rt*16 + q*4 + t;
        if (row < nrows)
          out[(size_t)row*ncols + col] = acc[rt][ct][t] + bv;
      }
    }
  }
}

// ---------------- fused edge scoring + online-softmax aggregation ----------------
// HID=128, 4 heads: wave per dst; lane holds channels 2l,2l+1; head = 16-lane group.
// Inner loop unrolled x4: 4 independent gathers + score chains merged into one
// online-softmax update (ILP fix for the serial dependency chain).

__global__ __launch_bounds__(256) void k_edge128(
  const float* __restrict__ xl, const float* __restrict__ xr,
  const int* __restrict__ rowptr, const int* __restrict__ csr_src, const float* __restrict__ csr_w,
  const float* __restrict__ We, const float* __restrict__ att,
  const float* __restrict__ bias, unsigned short* __restrict__ out, int n, int ET)
{
  int wid = threadIdx.x >> 6;
  int lane = threadIdx.x & 63;
  int node = blockIdx.x*4 + wid;
  if (node >= n) return;
  int ch = lane*2;
  float we0 = We[ch],  we1 = We[ch+1];
  float at0 = att[ch], at1 = att[ch+1];
  float2 xrv = *(const float2*)(xr + (size_t)node*128 + ch);
  float fxr0 = xrv.x, fxr1 = xrv.y;
  const float* xlc = xl + ch;
  int beg = rowptr[node], end = rowptr[node+1];
  if (beg < 0) beg = 0;
  if (end > ET) end = ET;
  float m = -1e30f, l = 0.f, a0 = 0.f, a1 = 0.f;

  for (int base = beg; base < end; base += 64){
    int idx = base + lane;
    int   sv = 0; float wv = 0.f;
    if (idx < end){ sv = csr_src[idx]; wv = csr_w[idx]; }
    if ((unsigned)sv >= (unsigned)n) sv = 0;
    int c = end - base; if (c > 64) c = 64;
    int i = 0;
    for (; i + 4 <= c; i += 4){
      int   s0 = __shfl(sv, i),   s1 = __shfl(sv, i+1),
            s2 = __shfl(sv, i+2), s3 = __shfl(sv, i+3);
      float w0 = __shfl(wv, i),   w1 = __shfl(wv, i+1),
            w2 = __shfl(wv, i+2), w3 = __shfl(wv, i+3);
      float2 v0 = *(const float2*)(xlc + (size_t)s0*128);
      float2 v1 = *(const float2*)(xlc + (size_t)s1*128);
      float2 v2 = *(const float2*)(xlc + (size_t)s2*128);
      float2 v3 = *(const float2*)(xlc + (size_t)s3*128);
      float p0, p1, p2, p3;
      {
        float t0 = v0.x + fxr0 + w0*we0, t1 = v0.y + fxr1 + w0*we1;
        t0 = t0 > 0.f ? t0 : 0.2f*t0;  t1 = t1 > 0.f ? t1 : 0.2f*t1;
        p0 = t0*at0 + t1*at1;
      }{
        float t0 = v1.x + fxr0 + w1*we0, t1 = v1.y + fxr1 + w1*we1;
        t0 = t0 > 0.f ? t0 : 0.2f*t0;  t1 = t1 > 0.f ? t1 : 0.2f*t1;
        p1 = t0*at0 + t1*at1;
      }{
        float t0 = v2.x + fxr0 + w2*we0, t1 = v2.y + fxr1 + w2*we1;
        t0 = t0 > 0.f ? t0 : 0.2f*t0;  t1 = t1 > 0.f ? t1 : 0.2f*t1;
        p2 = t0*at0 + t1*at1;
      }{
        float t0 = v3.x + fxr0 + w3*we0, t1 = v3.y + fxr1 + w3*we1;
        t0 = t0 > 0.f ? t0 : 0.2f*t0;  t1 = t1 > 0.f ? t1 : 0.2f*t1;
        p3 = t0*at0 + t1*at1;
      }
      for (int d = 1; d <= 8; d <<= 1){
        p0 += __shfl_xor(p0, d, 16);
        p1 += __shfl_xor(p1, d, 16);
        p2 += __shfl_xor(p2, d, 16);
        p3 += __shfl_xor(p3, d, 16);
      }
      float mx = fmaxf(fmaxf(p0, p1), fmaxf(p2, p3));
      float nm = fmaxf(m, mx);
      float sc = __expf(m - nm);
      float e0 = __expf(p0 - nm), e1 = __expf(p1 - nm);
      float e2 = __expf(p2 - nm), e3 = __expf(p3 - nm);
      l  = l*sc  + ((e0 + e1) + (e2 + e3));
      a0 = a0*sc + ((e0*v0.x + e1*v1.x) + (e2*v2.x + e3*v3.x));
      a1 = a1*sc + ((e0*v0.y + e1*v1.y) + (e2*v2.y + e3*v3.y));
      m = nm;
    }
    for (; i < c; i++){
      int   s = __shfl(sv, i);
      float w = __shfl(wv, i);
      float2 xv = *(const float2*)(xlc + (size_t)s*128);
      float t0 = xv.x + fxr0 + w*we0;
      float t1 = xv.y + fxr1 + w*we1;
      t0 = t0 > 0.f ? t0 : 0.2f*t0;
      t1 = t1 > 0.f ? t1 : 0.2f*t1;
      float p = t0*at0 + t1*at1;
      p += __shfl_xor(p, 1, 16);
      p += __shfl_xor(p, 2, 16);
      p += __shfl_xor(p, 4, 16);
      p += __shfl_xor(p, 8, 16);
      float nm = fmaxf(m, p);
      float sc = __expf(m - nm);
      float pe = __expf(p - nm);
      l  = l*sc  + pe;
      a0 = a0*sc + pe*xv.x;
      a1 = a1*sc + pe*xv.y;
      m = nm;
    }
  }
  float inv = 1.0f / (l + 1e-16f);
  float o0 = a0*inv + bias[ch];
  float o1 = a1*inv + bias[ch+1];
  o0 = o0 > 0.f ? o0 : (__expf(o0) - 1.0f);   // ELU (layers 0,1)
  o1 = o1 > 0.f ? o1 : (__expf(o1) - 1.0f);
  unsigned int packed = (unsigned int)f2bf(o0) | ((unsigned int)f2bf(o1) << 16);
  *(unsigned int*)(out + (size_t)node*128 + ch) = packed;
}

// OUT=64, 1 head: lane == channel, width-64 reduction; no ELU. Unrolled x4.
__global__ __launch_bounds__(256) void k_edge64(
  const float* __restrict__ xl, const float* __restrict__ xr,
  const int* __restrict__ rowptr, const int* __restrict__ csr_src, const float* __restrict__ csr_w,
  const float* __restrict__ We, const float* __restrict__ att,
  const float* __restrict__ bias, void* __restrict__ out, int n, int ET,
  const int* __restrict__ flag)
{
  int wid = threadIdx.x >> 6;
  int lane = threadIdx.x & 63;
  int node = blockIdx.x*4 + wid;
  if (node >= n) return;
  float we0 = We[lane];
  float at0 = att[lane];
  float fxr0 = xr[(size_t)node*64 + lane];
  const float* xlc = xl + lane;
  int beg = rowptr[node], end = rowptr[node+1];
  if (beg < 0) beg = 0;
  if (end > ET) end = ET;
  float m = -1e30f, l = 0.f, a0 = 0.f;

  for (int base = beg; base < end; base += 64){
    int idx = base + lane;
    int   sv = 0; float wv = 0.f;
    if (idx < end){ sv = csr_src[idx]; wv = csr_w[idx]; }
    if ((unsigned)sv >= (unsigned)n) sv = 0;
    int c = end - base; if (c > 64) c = 64;
    int i = 0;
    for (; i + 4 <= c; i += 4){
      int   s0 = __shfl(sv, i),   s1 = __shfl(sv, i+1),
            s2 = __shfl(sv, i+2), s3 = __shfl(sv, i+3);
      float w0 = __shfl(wv, i),   w1 = __shfl(wv, i+1),
            w2 = __shfl(wv, i+2), w3 = __shfl(wv, i+3);
      float x0 = xlc[(size_t)s0*64];
      float x1 = xlc[(size_t)s1*64];
      float x2 = xlc[(size_t)s2*64];
      float x3 = xlc[(size_t)s3*64];
      float t0 = x0 + fxr0 + w0*we0;  t0 = t0 > 0.f ? t0 : 0.2f*t0;
      float t1 = x1 + fxr0 + w1*we0;  t1 = t1 > 0.f ? t1 : 0.2f*t1;
      float t2 = x2 + fxr0 + w2*we0;  t2 = t2 > 0.f ? t2 : 0.2f*t2;
      float t3 = x3 + fxr0 + w3*we0;  t3 = t3 > 0.f ? t3 : 0.2f*t3;
      float p0 = t0*at0, p1 = t1*at0, p2 = t2*at0, p3 = t3*at0;
      for (int d = 1; d < 64; d <<= 1){
        p0 += __shfl_xor(p0, d);
        p1 += __shfl_xor(p1, d);
        p2 += __shfl_xor(p2, d);
        p3 += __shfl_xor(p3, d);
      }
      float mx = fmaxf(fmaxf(p0, p1), fmaxf(p2, p3));
      float nm = fmaxf(m, mx);
      float sc = __expf(m - nm);
      float e0 = __expf(p0 - nm), e1 = __expf(p1 - nm);
      float e2 = __expf(p2 - nm), e3 = __expf(p3 - nm);
      l  = l*sc  + ((e0 + e1) + (e2 + e3));
      a0 = a0*sc + ((e0*x0 + e1*x1) + (e2*x2 + e3*x3));
      m = nm;
    }
    for (; i < c; i++){
      int   s = __shfl(sv, i);
      float w = __shfl(wv, i);
      float x0 = xlc[(size_t)s*64];
      float t0 = x0 + fxr0 + w*we0;
      t0 = t0 > 0.f ? t0 : 0.2f*t0;
      float p = t0*at0;
      for (int d = 1; d < 64; d <<= 1) p += __shfl_xor(p, d);
      float nm = fmaxf(m, p);
      float sc = __expf(m - nm);
      float pe = __expf(p - nm);
      l  = l*sc  + pe;
      a0 = a0*sc + pe*x0;
      m = nm;
    }
  }
  float inv = 1.0f / (l + 1e-16f);
  float res = a0*inv + bias[lane];
  size_t oi = (size_t)node*64 + lane;
  if (flag[0]) ((float*)out)[oi] = res;
  else         ((unsigned short*)out)[oi] = f2bf(res);
}

// ---------------- host ----------------

extern "C" void kernel_launch(void* const* d_in, const int* in_sizes, int n_in,
                              void* d_out, int out_size, void* d_ws, size_t ws_size,
                              hipStream_t stream)
{
  (void)n_in; (void)out_size; (void)ws_size;
  const void* x   = d_in[0];
  const int*  ei  = (const int*)d_in[1];
  const void* ew  = d_in[2];

  const int N = in_sizes[0] / 128;
  const int E = in_sizes[2];
  const int ET = E + N;
  const int nB = (N + 255) / 256;   // scan blocks (<=1024 supported by k_scan2)

  char* p = (char*)d_ws;
  size_t off = 0;
  auto carve = [&](size_t bytes)->void* {
    void* r = p + off;
    off = (off + bytes + 255) & ~(size_t)255;
    return r;
  };
  int*            flag    = (int*)carve(4);
  int*            cnt     = (int*)carve((size_t)N*4);
  float*          wsum    = (float*)carve((size_t)N*4);
  int*            rowptr  = (int*)carve((size_t)(N+1)*4);
  int*            fill    = (int*)carve((size_t)N*4);
  int*            bsum    = (int*)carve((size_t)nB*4);
  int*            boff    = (int*)carve((size_t)nB*4);
  int*            csr_src = (int*)carve((size_t)ET*4);
  float*          csr_w   = (float*)carve((size_t)ET*4);
  float*          ewc     = (float*)carve((size_t)E*4);
  float*          prm     = (float*)carve(17*128*4);
  unsigned short* WT0l    = (unsigned short*)carve(128*128*2);
  unsigned short* WT0r    = (unsigned short*)carve(128*128*2);
  unsigned short* WT1l    = (unsigned short*)carve(128*128*2);
  unsigned short* WT1r    = (unsigned short*)carve(128*128*2);
  unsigned short* WT2l    = (unsigned short*)carve(128*64*2);
  unsigned short* WT2r    = (unsigned short*)carve(128*64*2);
  unsigned short* xc      = (unsigned short*)carve((size_t)N*128*2);
  float*          xlb     = (float*)carve((size_t)N*128*4);
  float*          xrb     = (float*)carve((size_t)N*128*4);
  unsigned short* hb      = (unsigned short*)carve((size_t)N*128*2);

  // canonical param layout: 17 slots of 128 floats
  float* bl0c = prm + 0*128;  float* br0c = prm + 1*128;
  float* We0c = prm + 2*128;  float* at0c = prm + 3*128;  float* bi0c = prm + 4*128;
  float* bl1c = prm + 5*128;  float* br1c = prm + 6*128;
  float* We1c = prm + 7*128;  float* at1c = prm + 8*128;  float* bi1c = prm + 9*128;
  float* bl2c = prm + 10*128; float* br2c = prm + 11*128;
  float* We2c = prm + 12*128; float* at2c = prm + 13*128; float* bi2c = prm + 14*128;

  hipMemsetAsync(cnt,  0, (size_t)N*4, stream);
  hipMemsetAsync(wsum, 0, (size_t)N*4, stream);

  k_detect<<<1, 256, 0, stream>>>((const unsigned short*)x, flag);

  ParamTab pt;
  {
    const void* srcs[17] = { d_in[4], d_in[6], d_in[7], d_in[8], d_in[9],
                             d_in[11], d_in[13], d_in[14], d_in[15], d_in[16],
                             d_in[18], d_in[20], d_in[21], d_in[22], d_in[23],
                             d_in[4], d_in[4] };
    float* dsts[17] = { bl0c, br0c, We0c, at0c, bi0c,
                        bl1c, br1c, We1c, at1c, bi1c,
                        bl2c, br2c, We2c, at2c, bi2c,
                        prm + 15*128, prm + 16*128 };
    int ns[17] = {128,128,128,128,128, 128,128,128,128,128, 64,64,64,64,64, 0,0};
    for (int i = 0; i < 17; i++){ pt.src[i] = srcs[i]; pt.dst[i] = dsts[i]; pt.n[i] = ns[i]; }
  }
  k_canon_params<<<17, 128, 0, stream>>>(pt, flag);
  k_canon_f32<<<(E+255)/256, 256, 0, stream>>>(ew, ewc, E, flag);
  k_canon_bf16<<<((size_t)N*128+255)/256, 256, 0, stream>>>(x, xc, N*128, flag);

  WTab wt;
  {
    const void* srcs[6] = { d_in[3], d_in[5], d_in[10], d_in[12], d_in[17], d_in[19] };
    unsigned short* dsts[6] = { WT0l, WT0r, WT1l, WT1r, WT2l, WT2r };
    int Ms[6] = {128, 128, 128, 128, 64, 64};
    for (int i = 0; i < 6; i++){ wt.src[i] = srcs[i]; wt.dst[i] = dsts[i]; wt.M[i] = Ms[i]; }
  }
  k_canonT<<<dim3(64, 6), 256, 0, stream>>>(wt, flag);

  // graph build
  k_hist <<<(E+255)/256, 256, 0, stream>>>(ei, ewc, cnt, wsum, E, N);
  k_scan1<<<nB, 256, 0, stream>>>(cnt, bsum, N);
  k_scan2<<<1, 1024, 0, stream>>>(bsum, boff, nB);
  k_scan3<<<nB, 256, 0, stream>>>(cnt, boff, rowptr, N);
  k_self <<<(N+255)/256, 256, 0, stream>>>(rowptr, cnt, wsum, fill, csr_src, csr_w, N, ET);
  k_scatter<<<(E+255)/256, 256, 0, stream>>>(ei, ewc, fill, csr_src, csr_w, E, N, ET);

  const int rowBlocks = (N + 63) / 64;

  // layer 0
  k_gemm<<<dim3(rowBlocks, 4), 64, 0, stream>>>(xc, WT0l, WT0r, bl0c, br0c, xlb, xrb, N, 128);
  k_edge128<<<(N+3)/4, 256, 0, stream>>>(xlb, xrb, rowptr, csr_src, csr_w, We0c, at0c, bi0c, hb, N, ET);

  // layer 1
  k_gemm<<<dim3(rowBlocks, 4), 64, 0, stream>>>(hb, WT1l, WT1r, bl1c, br1c, xlb, xrb, N, 128);
  k_edge128<<<(N+3)/4, 256, 0, stream>>>(xlb, xrb, rowptr, csr_src, csr_w, We1c, at1c, bi1c, hb, N, ET);

  // layer 2
  k_gemm<<<dim3(rowBlocks, 2), 64, 0, stream>>>(hb, WT2l, WT2r, bl2c, br2c, xlb, xrb, N, 64);
  k_edge64<<<(N+3)/4, 256, 0, stream>>>(xlb, xrb, rowptr, csr_src, csr_w, We2c, at2c, bi2c,
                                        d_out, N, ET, flag);
}